// Round 2
// baseline (1640.235 us; speedup 1.0000x reference)
//
#include <hip/hip_runtime.h>
#include <hip/hip_bf16.h>
#include <math.h>

// ---------------------------------------------------------------------------
// Shapes (fixed by the problem)
// ---------------------------------------------------------------------------
#define B_    4
#define S_    512
#define D_    1024
#define T_    2048          // B*S tokens
#define H_    16
#define HD_   64
#define E_    8
#define HID_  1792
#define D3_   3072

typedef unsigned short ushort_t;
typedef __bf16 bf16x8 __attribute__((ext_vector_type(8)));
typedef float  floatx4 __attribute__((ext_vector_type(4)));

__device__ inline float bf2f(ushort_t u) {
    return __uint_as_float(((unsigned)u) << 16);
}
__device__ inline ushort_t f2bf(float f) {
    __hip_bfloat16 h = __float2bfloat16(f);
    return __builtin_bit_cast(ushort_t, h);
}

// ---------------------------------------------------------------------------
// Transpose + fp32->bf16 convert:  in (batch, R, C) f32  ->  out (batch, C, R) bf16
// (used only for MoE weights)
// ---------------------------------------------------------------------------
__global__ __launch_bounds__(256) void transpose_bf16_kernel(
    const float* __restrict__ in, ushort_t* __restrict__ out, int R, int C)
{
    __shared__ float tile[32][33];
    const int bx = blockIdx.x * 32;           // c
    const int by = blockIdx.y * 32;           // r
    const size_t bofs = (size_t)blockIdx.z * R * C;
    const int tx = threadIdx.x & 31;
    const int ty = threadIdx.x >> 5;          // 0..7
#pragma unroll
    for (int i = 0; i < 4; i++) {
        int r = by + ty + i * 8;
        tile[ty + i * 8][tx] = in[bofs + (size_t)r * C + bx + tx];
    }
    __syncthreads();
#pragma unroll
    for (int i = 0; i < 4; i++) {
        int c = bx + ty + i * 8;
        out[bofs + (size_t)c * R + by + tx] = f2bf(tile[tx][ty + i * 8]);
    }
}

// ---------------------------------------------------------------------------
// LayerNorm: x (rows x 1024) f32 -> f32 out (if non-null) and bf16 out (if non-null)
// Precise: 1/sqrtf (IEEE), matches np 1/np.sqrt.
// ---------------------------------------------------------------------------
__global__ __launch_bounds__(256) void ln_kernel(
    const float* __restrict__ x, const float* __restrict__ g,
    const float* __restrict__ b, float* __restrict__ outf,
    ushort_t* __restrict__ outb)
{
    const int t = blockIdx.x;
    const int tid = threadIdx.x;
    const int wave = tid >> 6, lane = tid & 63;
    const float4 v = ((const float4*)(x + (size_t)t * D_))[tid];

    float s = v.x + v.y + v.z + v.w;
#pragma unroll
    for (int off = 32; off; off >>= 1) s += __shfl_xor(s, off);
    __shared__ float red1[4];
    __shared__ float red2[4];
    if (lane == 0) red1[wave] = s;
    __syncthreads();
    const float mu = (red1[0] + red1[1] + red1[2] + red1[3]) * (1.0f / D_);

    const float dx = v.x - mu, dy = v.y - mu, dz = v.z - mu, dw = v.w - mu;
    float vs = dx * dx + dy * dy + dz * dz + dw * dw;
#pragma unroll
    for (int off = 32; off; off >>= 1) vs += __shfl_xor(vs, off);
    if (lane == 0) red2[wave] = vs;
    __syncthreads();
    const float var = (red2[0] + red2[1] + red2[2] + red2[3]) * (1.0f / D_);
    const float rs = 1.0f / sqrtf(var + 1e-5f);

    const float4 gg = ((const float4*)g)[tid];
    const float4 bb = ((const float4*)b)[tid];
    float4 o;
    o.x = dx * rs * gg.x + bb.x;
    o.y = dy * rs * gg.y + bb.y;
    o.z = dz * rs * gg.z + bb.z;
    o.w = dw * rs * gg.w + bb.w;
    if (outf) ((float4*)(outf + (size_t)t * D_))[tid] = o;
    if (outb) {
        ushort4 ob;
        ob.x = f2bf(o.x); ob.y = f2bf(o.y); ob.z = f2bf(o.z); ob.w = f2bf(o.w);
        ((ushort4*)(outb + (size_t)t * D_))[tid] = ob;
    }
}

// ---------------------------------------------------------------------------
// f32 SGEMM: C(MxN) = A(MxK) * B(KxN) [+ res(MxN)]
// 128x128 tile, BK=16, 256 threads, 8x8 per thread. Full f32 fidelity.
// ---------------------------------------------------------------------------
__global__ __launch_bounds__(256) void sgemm_kernel(
    const float* __restrict__ A, const float* __restrict__ B,
    const float* __restrict__ res, float* __restrict__ C,
    int M, int N, int K)
{
    __shared__ float As[16][132];
    __shared__ float Bs[16][132];
    const int tid = threadIdx.x;
    const int m0 = blockIdx.y * 128, n0 = blockIdx.x * 128;
    const int tx = tid & 15, ty = tid >> 4;

    float acc[8][8] = {};

    const int ar = tid >> 2;            // 0..63
    const int ak = (tid & 3) * 4;       // 0,4,8,12
    const int bk = tid >> 4;            // 0..15
    const int bc = (tid & 15) * 4;      // 0..60

    const float* Ap0 = A + (size_t)(m0 + ar) * K + ak;
    const float* Ap1 = A + (size_t)(m0 + 64 + ar) * K + ak;
    const float* Bp  = B + (size_t)bk * N + n0 + bc;

    for (int k0 = 0; k0 < K; k0 += 16) {
        const float4 a0 = *(const float4*)(Ap0 + k0);
        const float4 a1 = *(const float4*)(Ap1 + k0);
        const float4 b0 = *(const float4*)(Bp + (size_t)k0 * N);
        const float4 b1 = *(const float4*)(Bp + (size_t)k0 * N + 64);
        __syncthreads();
        As[ak + 0][ar] = a0.x; As[ak + 1][ar] = a0.y;
        As[ak + 2][ar] = a0.z; As[ak + 3][ar] = a0.w;
        As[ak + 0][64 + ar] = a1.x; As[ak + 1][64 + ar] = a1.y;
        As[ak + 2][64 + ar] = a1.z; As[ak + 3][64 + ar] = a1.w;
        *(float4*)&Bs[bk][bc] = b0;
        *(float4*)&Bs[bk][bc + 64] = b1;
        __syncthreads();
#pragma unroll
        for (int k = 0; k < 16; k++) {
            const float4 av0 = *(const float4*)&As[k][ty * 8];
            const float4 av1 = *(const float4*)&As[k][ty * 8 + 4];
            const float4 bv0 = *(const float4*)&Bs[k][tx * 8];
            const float4 bv1 = *(const float4*)&Bs[k][tx * 8 + 4];
            const float a[8] = {av0.x, av0.y, av0.z, av0.w, av1.x, av1.y, av1.z, av1.w};
            const float b[8] = {bv0.x, bv0.y, bv0.z, bv0.w, bv1.x, bv1.y, bv1.z, bv1.w};
#pragma unroll
            for (int i = 0; i < 8; i++)
#pragma unroll
                for (int j = 0; j < 8; j++)
                    acc[i][j] = fmaf(a[i], b[j], acc[i][j]);
        }
    }

#pragma unroll
    for (int i = 0; i < 8; i++) {
        const int row = m0 + ty * 8 + i;
        const size_t base = (size_t)row * N + n0 + tx * 8;
        float4 o0, o1;
        o0.x = acc[i][0]; o0.y = acc[i][1]; o0.z = acc[i][2]; o0.w = acc[i][3];
        o1.x = acc[i][4]; o1.y = acc[i][5]; o1.z = acc[i][6]; o1.w = acc[i][7];
        if (res) {
            const float4 r0 = *(const float4*)(res + base);
            const float4 r1 = *(const float4*)(res + base + 4);
            o0.x += r0.x; o0.y += r0.y; o0.z += r0.z; o0.w += r0.w;
            o1.x += r1.x; o1.y += r1.y; o1.z += r1.z; o1.w += r1.w;
        }
        *(float4*)(C + base) = o0;
        *(float4*)(C + base + 4) = o1;
    }
}

// ---------------------------------------------------------------------------
// bf16 MFMA GEMM:  C(MxN) = A(MxK,bf16) * Bt(NxK,bf16)^T
// mode 0: C = acc
// mode 2: C += aux[row*auxStride+auxOff] * acc   (per-row scale, RMW)
// ---------------------------------------------------------------------------
__global__ __launch_bounds__(256) void gemm_bt_kernel(
    const ushort_t* __restrict__ A, const ushort_t* __restrict__ Bt,
    float* __restrict__ C, const float* __restrict__ aux,
    int M, int N, int K, int mode, int auxStride, int auxOff)
{
    __shared__ __align__(16) ushort_t As[64 * 32];
    __shared__ __align__(16) ushort_t Bs[64 * 32];
    const int tid = threadIdx.x;
    const int row0 = blockIdx.y * 64, col0 = blockIdx.x * 64;
    const int wave = tid >> 6, lane = tid & 63;
    const int wm = (wave >> 1) * 32, wn = (wave & 1) * 32;
    const int lm = lane & 15, lq = lane >> 4;

    floatx4 acc[2][2] = {};

    const int srow = tid >> 2;           // 0..63
    const int scol = (tid & 3) * 8;      // 0,8,16,24
    const ushort_t* Ap = A + (size_t)(row0 + srow) * K + scol;
    const ushort_t* Bp = Bt + (size_t)(col0 + srow) * K + scol;

    for (int k0 = 0; k0 < K; k0 += 32) {
        const uint4 av = *(const uint4*)(Ap + k0);
        const uint4 bv = *(const uint4*)(Bp + k0);
        __syncthreads();
        *(uint4*)(As + srow * 32 + scol) = av;
        *(uint4*)(Bs + srow * 32 + scol) = bv;
        __syncthreads();
        const bf16x8 a0 = *(const bf16x8*)(As + (wm + lm) * 32 + lq * 8);
        const bf16x8 a1 = *(const bf16x8*)(As + (wm + 16 + lm) * 32 + lq * 8);
        const bf16x8 b0 = *(const bf16x8*)(Bs + (wn + lm) * 32 + lq * 8);
        const bf16x8 b1 = *(const bf16x8*)(Bs + (wn + 16 + lm) * 32 + lq * 8);
        acc[0][0] = __builtin_amdgcn_mfma_f32_16x16x32_bf16(a0, b0, acc[0][0], 0, 0, 0);
        acc[0][1] = __builtin_amdgcn_mfma_f32_16x16x32_bf16(a0, b1, acc[0][1], 0, 0, 0);
        acc[1][0] = __builtin_amdgcn_mfma_f32_16x16x32_bf16(a1, b0, acc[1][0], 0, 0, 0);
        acc[1][1] = __builtin_amdgcn_mfma_f32_16x16x32_bf16(a1, b1, acc[1][1], 0, 0, 0);
    }

#pragma unroll
    for (int i = 0; i < 2; i++)
#pragma unroll
        for (int j = 0; j < 2; j++)
#pragma unroll
            for (int r = 0; r < 4; r++) {
                const int row = row0 + wm + i * 16 + lq * 4 + r;
                const int col = col0 + wn + j * 16 + lm;
                const size_t idx = (size_t)row * N + col;
                const float v = acc[i][j][r];
                if (mode == 0)      C[idx] = v;
                else                C[idx] += aux[row * auxStride + auxOff] * v;
            }
}

// ---------------------------------------------------------------------------
// RoPE cos/sin tables: replicate np f32 semantics.
// inv_freq = 1/powf(10000, j/64) with powf correctly rounded (via f64 pow);
// freqs = float(s) * inv_freq in f32; cos/sin of that f32 value (via f64).
// ---------------------------------------------------------------------------
__global__ __launch_bounds__(256) void rope_table_kernel(
    float* __restrict__ ctab, float* __restrict__ stab)
{
    const int i = blockIdx.x * 256 + threadIdx.x;   // S_*32
    if (i >= S_ * 32) return;
    const int s = i >> 5, p = i & 31;
    const double e = (double)(2 * p) / 64.0;
    const float pf = (float)pow(10000.0, e);
    const float invf = 1.0f / pf;
    const float fr = (float)s * invf;
    ctab[i] = (float)cos((double)fr);
    stab[i] = (float)sin((double)fr);
}

// ---------------------------------------------------------------------------
// RoPE in-place on qkv f32 (T x 3072): rotate q ([0,1024)) and k ([1024,2048))
// ---------------------------------------------------------------------------
__global__ __launch_bounds__(256) void rope_kernel(
    float* __restrict__ qkv, const float* __restrict__ ctab,
    const float* __restrict__ stab)
{
    const int n = blockIdx.x * 256 + threadIdx.x;     // T*H*32
    const int pair = n & 31;
    const int h = (n >> 5) & 15;
    const int t = n >> 9;
    const int s = t & (S_ - 1);
    const float c = ctab[s * 32 + pair];
    const float sn = stab[s * 32 + pair];
    const size_t base = (size_t)t * D3_ + h * HD_ + pair * 2;
    float x0 = qkv[base], x1 = qkv[base + 1];
    qkv[base]     = x0 * c - x1 * sn;
    qkv[base + 1] = x0 * sn + x1 * c;
    x0 = qkv[base + D_]; x1 = qkv[base + D_ + 1];
    qkv[base + D_]     = x0 * c - x1 * sn;
    qkv[base + D_ + 1] = x0 * sn + x1 * c;
}

// ---------------------------------------------------------------------------
// Flash-style causal attention, f32 in/out, precise expf.
// grid (16 qtiles, 16 heads, 4 batch), block 256 = 4 waves.
// ---------------------------------------------------------------------------
__global__ __launch_bounds__(256) void attn_kernel(
    const float* __restrict__ qkv, float* __restrict__ out)
{
    __shared__ float kbuf[64][65];
    __shared__ float vbuf[64][65];
    __shared__ float qs[32][64];
    __shared__ float ps[4][8][64];

    const int b = blockIdx.z, h = blockIdx.y, qt = blockIdx.x;
    const int tid = threadIdx.x, wave = tid >> 6, lane = tid & 63;
    const int q0 = qt * 32;

    for (int i = tid; i < 32 * 64; i += 256) {
        const int qi = i >> 6, d = i & 63;
        const int t = b * S_ + q0 + qi;
        qs[qi][d] = qkv[(size_t)t * D3_ + h * HD_ + d];
    }

    float m[8], l[8], O[8];
#pragma unroll
    for (int qi = 0; qi < 8; qi++) { m[qi] = -INFINITY; l[qi] = 0.f; O[qi] = 0.f; }

    const int maxS = q0 + 31;
    for (int c0 = 0; c0 <= maxS; c0 += 64) {
        __syncthreads();
        for (int i = tid; i < 64 * 16; i += 256) {
            const int key = i >> 4, d4 = (i & 15) * 4;
            const int t = b * S_ + c0 + key;
            const float4 kv = *(const float4*)(qkv + (size_t)t * D3_ + D_ + h * HD_ + d4);
            const float4 vv = *(const float4*)(qkv + (size_t)t * D3_ + 2 * D_ + h * HD_ + d4);
            kbuf[key][d4 + 0] = kv.x; kbuf[key][d4 + 1] = kv.y;
            kbuf[key][d4 + 2] = kv.z; kbuf[key][d4 + 3] = kv.w;
            vbuf[key][d4 + 0] = vv.x; vbuf[key][d4 + 1] = vv.y;
            vbuf[key][d4 + 2] = vv.z; vbuf[key][d4 + 3] = vv.w;
        }
        __syncthreads();

        const int kglob = c0 + lane;
        float sc[8];
#pragma unroll
        for (int qi = 0; qi < 8; qi++) sc[qi] = 0.f;
#pragma unroll 8
        for (int d = 0; d < 64; d++) {
            const float kv = kbuf[lane][d];
#pragma unroll
            for (int qi = 0; qi < 8; qi++)
                sc[qi] = fmaf(qs[wave * 8 + qi][d], kv, sc[qi]);
        }
#pragma unroll
        for (int qi = 0; qi < 8; qi++) {
            const int s = q0 + wave * 8 + qi;
            float v = (kglob <= s) ? sc[qi] * 0.125f : -INFINITY;
            float cmax = v;
#pragma unroll
            for (int off = 32; off; off >>= 1) cmax = fmaxf(cmax, __shfl_xor(cmax, off));
            const float mnew = fmaxf(m[qi], cmax);
            const float alpha = expf(m[qi] - mnew);
            const float p = (v == -INFINITY) ? 0.f : expf(v - mnew);
            float psum = p;
#pragma unroll
            for (int off = 32; off; off >>= 1) psum += __shfl_xor(psum, off);
            l[qi] = l[qi] * alpha + psum;
            m[qi] = mnew;
            ps[wave][qi][lane] = p;
            sc[qi] = alpha;
        }
#pragma unroll
        for (int qi = 0; qi < 8; qi++) O[qi] *= sc[qi];
#pragma unroll 8
        for (int j = 0; j < 64; j++) {
            const float vv = vbuf[j][lane];
#pragma unroll
            for (int qi = 0; qi < 8; qi++)
                O[qi] = fmaf(ps[wave][qi][j], vv, O[qi]);
        }
    }

#pragma unroll
    for (int qi = 0; qi < 8; qi++) {
        const int t = b * S_ + q0 + wave * 8 + qi;
        out[(size_t)t * D_ + h * HD_ + lane] = O[qi] / l[qi];
    }
}

// ---------------------------------------------------------------------------
// Copy f32 (float4 granular)
// ---------------------------------------------------------------------------
__global__ __launch_bounds__(256) void copy_f32_kernel(
    const float* __restrict__ in, float* __restrict__ out, int n4)
{
    const int i = blockIdx.x * 256 + threadIdx.x;
    if (i < n4) ((float4*)out)[i] = ((const float4*)in)[i];
}

// ---------------------------------------------------------------------------
// h = silu(g) * u   -> bf16
// ---------------------------------------------------------------------------
__global__ __launch_bounds__(256) void silu_mul_kernel(
    const float* __restrict__ g, const float* __restrict__ u,
    ushort_t* __restrict__ h, int n4)
{
    const int i = blockIdx.x * 256 + threadIdx.x;
    if (i < n4) {
        const float4 gv = ((const float4*)g)[i];
        const float4 uv = ((const float4*)u)[i];
        ushort4 o;
        o.x = f2bf(gv.x / (1.f + __expf(-gv.x)) * uv.x);
        o.y = f2bf(gv.y / (1.f + __expf(-gv.y)) * uv.y);
        o.z = f2bf(gv.z / (1.f + __expf(-gv.z)) * uv.z);
        o.w = f2bf(gv.w / (1.f + __expf(-gv.w)) * uv.w);
        ((ushort4*)h)[i] = o;
    }
}

// ---------------------------------------------------------------------------
// Gating. Logits = f32-accumulated dot of bf16(xn2) and bf16(gate_w), then
// ROUNDED TO BF16 (XLA's bf16@bf16->bf16 result), matching the reference.
// Top-2 with lowest-index tie-break (lax.top_k), softmax weights, probs.
// ---------------------------------------------------------------------------
__global__ __launch_bounds__(64) void gate_kernel(
    const ushort_t* __restrict__ xn2, const float* __restrict__ gate_w,
    float* __restrict__ cw, float* __restrict__ dist)
{
    const int t = blockIdx.x;
    const int lane = threadIdx.x;
    float acc[8] = {0, 0, 0, 0, 0, 0, 0, 0};
    for (int d = lane; d < D_; d += 64) {
        const float xv = bf2f(xn2[(size_t)t * D_ + d]);
        const float4 g0 = ((const float4*)(gate_w + d * 8))[0];
        const float4 g1 = ((const float4*)(gate_w + d * 8))[1];
        acc[0] = fmaf(xv, bf2f(f2bf(g0.x)), acc[0]);
        acc[1] = fmaf(xv, bf2f(f2bf(g0.y)), acc[1]);
        acc[2] = fmaf(xv, bf2f(f2bf(g0.z)), acc[2]);
        acc[3] = fmaf(xv, bf2f(f2bf(g0.w)), acc[3]);
        acc[4] = fmaf(xv, bf2f(f2bf(g1.x)), acc[4]);
        acc[5] = fmaf(xv, bf2f(f2bf(g1.y)), acc[5]);
        acc[6] = fmaf(xv, bf2f(f2bf(g1.z)), acc[6]);
        acc[7] = fmaf(xv, bf2f(f2bf(g1.w)), acc[7]);
    }
#pragma unroll
    for (int e = 0; e < 8; e++) {
#pragma unroll
        for (int off = 32; off; off >>= 1) acc[e] += __shfl_xor(acc[e], off);
        acc[e] = bf2f(f2bf(acc[e]));   // bf16 result of the bf16 matmul
    }

    if (lane == 0) {
        int i1 = 0;
        for (int e = 1; e < 8; e++) if (acc[e] > acc[i1]) i1 = e;
        int i2 = (i1 == 0) ? 1 : 0;
        for (int e = 0; e < 8; e++) if (e != i1 && acc[e] > acc[i2]) i2 = e;
        const float e2 = expf(acc[i2] - acc[i1]);
        const float w1 = 1.f / (1.f + e2);
        const float w2 = e2 * w1;
        for (int e = 0; e < 8; e++) {
            float w = (e == i1) ? w1 : ((e == i2) ? w2 : 0.f);
            cw[t * 8 + e] = w;
        }
        const float mx = acc[i1];
        float se = 0.f, pe[8];
        for (int e = 0; e < 8; e++) { pe[e] = expf(acc[e] - mx); se += pe[e]; }
        const float inv = 1.f / (se * (float)T_);
        for (int e = 0; e < 8; e++) atomicAdd(&dist[e], pe[e] * inv);
    }
}

__global__ void zero_dist_kernel(float* __restrict__ dist)
{
    if (threadIdx.x < 8) dist[threadIdx.x] = 0.f;
}

__global__ void finalize_kernel(const float* __restrict__ dist, float* __restrict__ out)
{
    if (threadIdx.x == 0) {
        float s2 = 0.f;
        for (int e = 0; e < 8; e++) s2 += dist[e] * dist[e];
        out[(size_t)T_ * D_] = (float)E_ * s2;
    }
    if (threadIdx.x < 8) out[(size_t)T_ * D_ + 1 + threadIdx.x] = dist[threadIdx.x];
}

// ---------------------------------------------------------------------------
// Launch
// ---------------------------------------------------------------------------
extern "C" void kernel_launch(void* const* d_in, const int* in_sizes, int n_in,
                              void* d_out, int out_size, void* d_ws, size_t ws_size,
                              hipStream_t stream)
{
    const float* x      = (const float*)d_in[0];
    const float* ln1_g  = (const float*)d_in[1];
    const float* ln1_b  = (const float*)d_in[2];
    const float* ln2_g  = (const float*)d_in[3];
    const float* ln2_b  = (const float*)d_in[4];
    const float* w_qkv  = (const float*)d_in[5];
    const float* w_o    = (const float*)d_in[6];
    const float* gate_w = (const float*)d_in[7];
    const float* w_gate = (const float*)d_in[8];
    const float* w_up   = (const float*)d_in[9];
    const float* w_down = (const float*)d_in[10];
    float* out = (float*)d_out;

    char* ws = (char*)d_ws;
    size_t off = 0;
    auto alloc = [&](size_t bytes) { size_t o = off; off += (bytes + 255) & ~(size_t)255; return o; };
    ushort_t* wgT   = (ushort_t*)(ws + alloc((size_t)E_ * HID_ * D_ * 2));
    ushort_t* wuT   = (ushort_t*)(ws + alloc((size_t)E_ * HID_ * D_ * 2));
    ushort_t* wdT   = (ushort_t*)(ws + alloc((size_t)E_ * D_ * HID_ * 2));
    float*    xn    = (float*)   (ws + alloc((size_t)T_ * D_ * 4));
    float*    qkv   = (float*)   (ws + alloc((size_t)T_ * D3_ * 4));
    float*    attnO = (float*)   (ws + alloc((size_t)T_ * D_ * 4));
    float*    x1    = (float*)   (ws + alloc((size_t)T_ * D_ * 4));
    ushort_t* xn2   = (ushort_t*)(ws + alloc((size_t)T_ * D_ * 2));
    float*    gbuf  = (float*)   (ws + alloc((size_t)T_ * HID_ * 4));
    float*    ubuf  = (float*)   (ws + alloc((size_t)T_ * HID_ * 4));
    ushort_t* hbuf  = (ushort_t*)(ws + alloc((size_t)T_ * HID_ * 2));
    float*    cw    = (float*)   (ws + alloc((size_t)T_ * E_ * 4));
    float*    dist  = (float*)   (ws + alloc(64));
    float*    ctab  = (float*)   (ws + alloc((size_t)S_ * 32 * 4));
    float*    stab  = (float*)   (ws + alloc((size_t)S_ * 32 * 4));
    (void)ws_size; (void)in_sizes; (void)n_in; (void)out_size;

    // MoE weight transposes -> bf16 N x K
    hipLaunchKernelGGL(transpose_bf16_kernel, dim3(HID_ / 32, D_ / 32, E_), dim3(256), 0, stream,
                       w_gate, wgT, D_, HID_);
    hipLaunchKernelGGL(transpose_bf16_kernel, dim3(HID_ / 32, D_ / 32, E_), dim3(256), 0, stream,
                       w_up, wuT, D_, HID_);
    hipLaunchKernelGGL(transpose_bf16_kernel, dim3(D_ / 32, HID_ / 32, E_), dim3(256), 0, stream,
                       w_down, wdT, HID_, D_);

    // RoPE tables
    hipLaunchKernelGGL(rope_table_kernel, dim3((S_ * 32 + 255) / 256), dim3(256), 0, stream,
                       ctab, stab);

    // LN1 (f32 out)
    hipLaunchKernelGGL(ln_kernel, dim3(T_), dim3(256), 0, stream,
                       x, ln1_g, ln1_b, xn, (ushort_t*)nullptr);

    // QKV f32 SGEMM (2048 x 3072 x 1024)
    hipLaunchKernelGGL(sgemm_kernel, dim3(D3_ / 128, T_ / 128), dim3(256), 0, stream,
                       xn, w_qkv, (const float*)nullptr, qkv, T_, D3_, D_);

    // RoPE
    hipLaunchKernelGGL(rope_kernel, dim3(T_ * H_ * 32 / 256), dim3(256), 0, stream,
                       qkv, ctab, stab);

    // attention (f32)
    hipLaunchKernelGGL(attn_kernel, dim3(S_ / 32, H_, B_), dim3(256), 0, stream, qkv, attnO);

    // W_O f32 SGEMM + residual -> x1
    hipLaunchKernelGGL(sgemm_kernel, dim3(D_ / 128, T_ / 128), dim3(256), 0, stream,
                       attnO, w_o, x, x1, T_, D_, D_);

    // out x-region = x1
    hipLaunchKernelGGL(copy_f32_kernel, dim3(T_ * D_ / 4 / 256), dim3(256), 0, stream,
                       x1, out, T_ * D_ / 4);

    // LN2 (bf16 out)
    hipLaunchKernelGGL(ln_kernel, dim3(T_), dim3(256), 0, stream,
                       x1, ln2_g, ln2_b, (float*)nullptr, xn2);

    // gating
    hipLaunchKernelGGL(zero_dist_kernel, dim3(1), dim3(64), 0, stream, dist);
    hipLaunchKernelGGL(gate_kernel, dim3(T_), dim3(64), 0, stream, xn2, gate_w, cw, dist);
    hipLaunchKernelGGL(finalize_kernel, dim3(1), dim3(64), 0, stream, dist, out);

    // MoE dense (bf16 MFMA), expert by expert
    for (int e = 0; e < E_; e++) {
        const ushort_t* wg = wgT + (size_t)e * HID_ * D_;
        const ushort_t* wu = wuT + (size_t)e * HID_ * D_;
        const ushort_t* wd = wdT + (size_t)e * D_ * HID_;
        hipLaunchKernelGGL(gemm_bt_kernel, dim3(HID_ / 64, T_ / 64), dim3(256), 0, stream,
                           xn2, wg, gbuf, (const float*)nullptr, T_, HID_, D_, 0, 0, 0);
        hipLaunchKernelGGL(gemm_bt_kernel, dim3(HID_ / 64, T_ / 64), dim3(256), 0, stream,
                           xn2, wu, ubuf, (const float*)nullptr, T_, HID_, D_, 0, 0, 0);
        hipLaunchKernelGGL(silu_mul_kernel, dim3(T_ * HID_ / 4 / 256), dim3(256), 0, stream,
                           gbuf, ubuf, hbuf, T_ * HID_ / 4);
        hipLaunchKernelGGL(gemm_bt_kernel, dim3(D_ / 64, T_ / 64), dim3(256), 0, stream,
                           hbuf, wd, out, cw, T_, D_, HID_, 2, 8, e);
    }
}

// Round 3
// 1026.261 us; speedup vs baseline: 1.5983x; 1.5983x over previous
//
#include <hip/hip_runtime.h>
#include <hip/hip_bf16.h>
#include <math.h>

// ---------------------------------------------------------------------------
// Shapes (fixed by the problem)
// ---------------------------------------------------------------------------
#define B_    4
#define S_    512
#define D_    1024
#define T_    2048          // B*S tokens
#define H_    16
#define HD_   64
#define E_    8
#define HID_  1792
#define D3_   3072
#define GU_   (2 * HID_)    // 3584 interleaved gate/up columns

typedef unsigned short ushort_t;
typedef __bf16 bf16x8 __attribute__((ext_vector_type(8)));
typedef float  floatx4 __attribute__((ext_vector_type(4)));

__device__ inline float bf2f(ushort_t u) {
    return __uint_as_float(((unsigned)u) << 16);
}
__device__ inline ushort_t f2bf(float f) {
    __hip_bfloat16 h = __float2bfloat16(f);
    return __builtin_bit_cast(ushort_t, h);
}

// async 16B/lane global->LDS; lds dest must be wave-uniform base (+lane*16 by HW)
__device__ __forceinline__ void gl2lds16(const ushort_t* g, ushort_t* l) {
    __builtin_amdgcn_global_load_lds(
        (const __attribute__((address_space(1))) void*)g,
        (__attribute__((address_space(3))) void*)l, 16, 0, 0);
}

// ---------------------------------------------------------------------------
// Transpose + fp32->bf16: in (z,R,C) f32 -> out[z*outEstride + (c*mul+add)*R + r]
// ---------------------------------------------------------------------------
__global__ __launch_bounds__(256) void transpose_bf16_kernel(
    const float* __restrict__ in, ushort_t* __restrict__ out,
    int R, int C, int mul, int add, long outEstride)
{
    __shared__ float tile[32][33];
    const int bx = blockIdx.x * 32;           // c
    const int by = blockIdx.y * 32;           // r
    const size_t iofs = (size_t)blockIdx.z * R * C;
    const size_t oofs = (size_t)blockIdx.z * outEstride;
    const int tx = threadIdx.x & 31;
    const int ty = threadIdx.x >> 5;          // 0..7
#pragma unroll
    for (int i = 0; i < 4; i++) {
        int r = by + ty + i * 8;
        tile[ty + i * 8][tx] = in[iofs + (size_t)r * C + bx + tx];
    }
    __syncthreads();
#pragma unroll
    for (int i = 0; i < 4; i++) {
        int c = bx + ty + i * 8;
        out[oofs + (size_t)(c * mul + add) * R + by + tx] = f2bf(tile[tx][ty + i * 8]);
    }
}

// ---------------------------------------------------------------------------
// LayerNorm: x (rows x 1024) f32 -> f32 out and/or bf16 out
// ---------------------------------------------------------------------------
__global__ __launch_bounds__(256) void ln_kernel(
    const float* __restrict__ x, const float* __restrict__ g,
    const float* __restrict__ b, float* __restrict__ outf,
    ushort_t* __restrict__ outb)
{
    const int t = blockIdx.x;
    const int tid = threadIdx.x;
    const int wave = tid >> 6, lane = tid & 63;
    const float4 v = ((const float4*)(x + (size_t)t * D_))[tid];

    float s = v.x + v.y + v.z + v.w;
#pragma unroll
    for (int off = 32; off; off >>= 1) s += __shfl_xor(s, off);
    __shared__ float red1[4];
    __shared__ float red2[4];
    if (lane == 0) red1[wave] = s;
    __syncthreads();
    const float mu = (red1[0] + red1[1] + red1[2] + red1[3]) * (1.0f / D_);

    const float dx = v.x - mu, dy = v.y - mu, dz = v.z - mu, dw = v.w - mu;
    float vs = dx * dx + dy * dy + dz * dz + dw * dw;
#pragma unroll
    for (int off = 32; off; off >>= 1) vs += __shfl_xor(vs, off);
    if (lane == 0) red2[wave] = vs;
    __syncthreads();
    const float var = (red2[0] + red2[1] + red2[2] + red2[3]) * (1.0f / D_);
    const float rs = 1.0f / sqrtf(var + 1e-5f);

    const float4 gg = ((const float4*)g)[tid];
    const float4 bb = ((const float4*)b)[tid];
    float4 o;
    o.x = dx * rs * gg.x + bb.x;
    o.y = dy * rs * gg.y + bb.y;
    o.z = dz * rs * gg.z + bb.z;
    o.w = dw * rs * gg.w + bb.w;
    if (outf) ((float4*)(outf + (size_t)t * D_))[tid] = o;
    if (outb) {
        ushort4 ob;
        ob.x = f2bf(o.x); ob.y = f2bf(o.y); ob.z = f2bf(o.z); ob.w = f2bf(o.w);
        ((ushort4*)(outb + (size_t)t * D_))[tid] = ob;
    }
}

// ---------------------------------------------------------------------------
// f32 SGEMM: C(MxN) = A(MxK) * B(KxN) [+ res]; 128x128 tile, BK=16, 8x8/thr
// ---------------------------------------------------------------------------
__global__ __launch_bounds__(256) void sgemm_kernel(
    const float* __restrict__ A, const float* __restrict__ B,
    const float* __restrict__ res, float* __restrict__ C,
    int M, int N, int K)
{
    __shared__ float As[16][132];
    __shared__ float Bs[16][132];
    const int tid = threadIdx.x;
    const int m0 = blockIdx.y * 128, n0 = blockIdx.x * 128;
    const int tx = tid & 15, ty = tid >> 4;

    float acc[8][8] = {};

    const int ar = tid >> 2;            // 0..63
    const int ak = (tid & 3) * 4;       // 0,4,8,12
    const int bk = tid >> 4;            // 0..15
    const int bc = (tid & 15) * 4;      // 0..60

    const float* Ap0 = A + (size_t)(m0 + ar) * K + ak;
    const float* Ap1 = A + (size_t)(m0 + 64 + ar) * K + ak;
    const float* Bp  = B + (size_t)bk * N + n0 + bc;

    for (int k0 = 0; k0 < K; k0 += 16) {
        const float4 a0 = *(const float4*)(Ap0 + k0);
        const float4 a1 = *(const float4*)(Ap1 + k0);
        const float4 b0 = *(const float4*)(Bp + (size_t)k0 * N);
        const float4 b1 = *(const float4*)(Bp + (size_t)k0 * N + 64);
        __syncthreads();
        As[ak + 0][ar] = a0.x; As[ak + 1][ar] = a0.y;
        As[ak + 2][ar] = a0.z; As[ak + 3][ar] = a0.w;
        As[ak + 0][64 + ar] = a1.x; As[ak + 1][64 + ar] = a1.y;
        As[ak + 2][64 + ar] = a1.z; As[ak + 3][64 + ar] = a1.w;
        *(float4*)&Bs[bk][bc] = b0;
        *(float4*)&Bs[bk][bc + 64] = b1;
        __syncthreads();
#pragma unroll
        for (int k = 0; k < 16; k++) {
            const float4 av0 = *(const float4*)&As[k][ty * 8];
            const float4 av1 = *(const float4*)&As[k][ty * 8 + 4];
            const float4 bv0 = *(const float4*)&Bs[k][tx * 8];
            const float4 bv1 = *(const float4*)&Bs[k][tx * 8 + 4];
            const float a[8] = {av0.x, av0.y, av0.z, av0.w, av1.x, av1.y, av1.z, av1.w};
            const float b[8] = {bv0.x, bv0.y, bv0.z, bv0.w, bv1.x, bv1.y, bv1.z, bv1.w};
#pragma unroll
            for (int i = 0; i < 8; i++)
#pragma unroll
                for (int j = 0; j < 8; j++)
                    acc[i][j] = fmaf(a[i], b[j], acc[i][j]);
        }
    }

#pragma unroll
    for (int i = 0; i < 8; i++) {
        const int row = m0 + ty * 8 + i;
        const size_t base = (size_t)row * N + n0 + tx * 8;
        float4 o0, o1;
        o0.x = acc[i][0]; o0.y = acc[i][1]; o0.z = acc[i][2]; o0.w = acc[i][3];
        o1.x = acc[i][4]; o1.y = acc[i][5]; o1.z = acc[i][6]; o1.w = acc[i][7];
        if (res) {
            const float4 r0 = *(const float4*)(res + base);
            const float4 r1 = *(const float4*)(res + base + 4);
            o0.x += r0.x; o0.y += r0.y; o0.z += r0.z; o0.w += r0.w;
            o1.x += r1.x; o1.y += r1.y; o1.z += r1.z; o1.w += r1.w;
        }
        *(float4*)(C + base) = o0;
        *(float4*)(C + base + 4) = o1;
    }
}

// ---------------------------------------------------------------------------
// Fused gate+up MoE GEMM (m97 structure): 128x128 tile, BK=32, global_load_lds.
// A: xn2 (T x 1024 bf16). Bgu: per-expert 3584 x 1024 bf16 with g/u columns
// interleaved (col 2j = gate j, col 2j+1 = up j). Epilogue: silu(g)*u -> Hout.
// grid (28, 16, E), block 256.
// ---------------------------------------------------------------------------
__global__ __launch_bounds__(256) void gateup_kernel(
    const ushort_t* __restrict__ A, const ushort_t* __restrict__ Bgu,
    ushort_t* __restrict__ Hout)
{
    __shared__ __align__(16) ushort_t As[128 * 32];
    __shared__ __align__(16) ushort_t Bs[128 * 32];
    const int e = blockIdx.z;
    const int col0 = blockIdx.x * 128;
    const int row0 = blockIdx.y * 128;
    const ushort_t* Bt = Bgu + (size_t)e * GU_ * D_;
    ushort_t* Hp = Hout + (size_t)e * T_ * HID_;

    const int tid = threadIdx.x, w = tid >> 6, lane = tid & 63;
    const int lr = lane >> 2, lc = (lane & 3) * 8;
    const int wm = (w >> 1) * 64, wn = (w & 1) * 64;
    const int lm = lane & 15, lq = lane >> 4;

    floatx4 acc[4][4] = {};

    const ushort_t* Ap = A + (size_t)(row0 + w * 16 + lr) * D_ + lc;
    const ushort_t* Bp = Bt + (size_t)(col0 + w * 16 + lr) * D_ + lc;
    ushort_t* lA = As + w * 512;
    ushort_t* lB = Bs + w * 512;

    for (int k0 = 0; k0 < D_; k0 += 32) {
        __syncthreads();                       // all waves done reading LDS
        gl2lds16(Ap + k0, lA);
        gl2lds16(Ap + k0 + (size_t)64 * D_, lA + 2048);
        gl2lds16(Bp + k0, lB);
        gl2lds16(Bp + k0 + (size_t)64 * D_, lB + 2048);
        __syncthreads();                       // vmcnt(0) drained before barrier
        bf16x8 a[4], b[4];
#pragma unroll
        for (int i = 0; i < 4; i++)
            a[i] = *(const bf16x8*)(As + (wm + i * 16 + lm) * 32 + lq * 8);
#pragma unroll
        for (int j = 0; j < 4; j++)
            b[j] = *(const bf16x8*)(Bs + (wn + j * 16 + lm) * 32 + lq * 8);
#pragma unroll
        for (int i = 0; i < 4; i++)
#pragma unroll
            for (int j = 0; j < 4; j++)
                acc[i][j] = __builtin_amdgcn_mfma_f32_16x16x32_bf16(a[i], b[j], acc[i][j], 0, 0, 0);
    }

    // epilogue: adjacent lanes hold (gate, up) for the same hidden unit
#pragma unroll
    for (int i = 0; i < 4; i++)
#pragma unroll
        for (int j = 0; j < 4; j++)
#pragma unroll
            for (int r = 0; r < 4; r++) {
                const float v = acc[i][j][r];
                const float vp = __shfl_xor(v, 1);
                const float g = (lm & 1) ? vp : v;
                const float u = (lm & 1) ? v : vp;
                const float h = g / (1.f + __expf(-g)) * u;
                if (!(lm & 1)) {
                    const int row = row0 + wm + i * 16 + lq * 4 + r;
                    const int col = col0 + wn + j * 16 + lm;    // even
                    Hp[(size_t)row * HID_ + (col >> 1)] = f2bf(h);
                }
            }
}

// ---------------------------------------------------------------------------
// MoE down GEMM: out[row] += cw[row,e] * (H[e] @ wd[e]^T).  grid (8, 16, E).
// ---------------------------------------------------------------------------
__global__ __launch_bounds__(256) void down_kernel(
    const ushort_t* __restrict__ Hall, const ushort_t* __restrict__ Wd,
    const float* __restrict__ cw, float* __restrict__ out)
{
    __shared__ __align__(16) ushort_t As[128 * 32];
    __shared__ __align__(16) ushort_t Bs[128 * 32];
    const int e = blockIdx.z;
    const int col0 = blockIdx.x * 128;
    const int row0 = blockIdx.y * 128;
    const ushort_t* A = Hall + (size_t)e * T_ * HID_;
    const ushort_t* Bt = Wd + (size_t)e * D_ * HID_;

    const int tid = threadIdx.x, w = tid >> 6, lane = tid & 63;
    const int lr = lane >> 2, lc = (lane & 3) * 8;
    const int wm = (w >> 1) * 64, wn = (w & 1) * 64;
    const int lm = lane & 15, lq = lane >> 4;

    floatx4 acc[4][4] = {};

    const ushort_t* Ap = A + (size_t)(row0 + w * 16 + lr) * HID_ + lc;
    const ushort_t* Bp = Bt + (size_t)(col0 + w * 16 + lr) * HID_ + lc;
    ushort_t* lA = As + w * 512;
    ushort_t* lB = Bs + w * 512;

    for (int k0 = 0; k0 < HID_; k0 += 32) {
        __syncthreads();
        gl2lds16(Ap + k0, lA);
        gl2lds16(Ap + k0 + (size_t)64 * HID_, lA + 2048);
        gl2lds16(Bp + k0, lB);
        gl2lds16(Bp + k0 + (size_t)64 * HID_, lB + 2048);
        __syncthreads();
        bf16x8 a[4], b[4];
#pragma unroll
        for (int i = 0; i < 4; i++)
            a[i] = *(const bf16x8*)(As + (wm + i * 16 + lm) * 32 + lq * 8);
#pragma unroll
        for (int j = 0; j < 4; j++)
            b[j] = *(const bf16x8*)(Bs + (wn + j * 16 + lm) * 32 + lq * 8);
#pragma unroll
        for (int i = 0; i < 4; i++)
#pragma unroll
            for (int j = 0; j < 4; j++)
                acc[i][j] = __builtin_amdgcn_mfma_f32_16x16x32_bf16(a[i], b[j], acc[i][j], 0, 0, 0);
    }

#pragma unroll
    for (int i = 0; i < 4; i++)
#pragma unroll
        for (int r = 0; r < 4; r++) {
            const int row = row0 + wm + i * 16 + lq * 4 + r;
            const float scale = cw[row * E_ + e];
            if (scale != 0.f) {
#pragma unroll
                for (int j = 0; j < 4; j++) {
                    const int col = col0 + wn + j * 16 + lm;
                    atomicAdd(&out[(size_t)row * D_ + col], scale * acc[i][j][r]);
                }
            }
        }
}

// ---------------------------------------------------------------------------
// RoPE cos/sin tables (np f32 semantics via f64 pow/cos/sin)
// ---------------------------------------------------------------------------
__global__ __launch_bounds__(256) void rope_table_kernel(
    float* __restrict__ ctab, float* __restrict__ stab)
{
    const int i = blockIdx.x * 256 + threadIdx.x;   // S_*32
    if (i >= S_ * 32) return;
    const int s = i >> 5, p = i & 31;
    const double e = (double)(2 * p) / 64.0;
    const float pf = (float)pow(10000.0, e);
    const float invf = 1.0f / pf;
    const float fr = (float)s * invf;
    ctab[i] = (float)cos((double)fr);
    stab[i] = (float)sin((double)fr);
}

// ---------------------------------------------------------------------------
// RoPE in-place on qkv f32 (T x 3072): rotate q and k
// ---------------------------------------------------------------------------
__global__ __launch_bounds__(256) void rope_kernel(
    float* __restrict__ qkv, const float* __restrict__ ctab,
    const float* __restrict__ stab)
{
    const int n = blockIdx.x * 256 + threadIdx.x;     // T*H*32
    const int pair = n & 31;
    const int h = (n >> 5) & 15;
    const int t = n >> 9;
    const int s = t & (S_ - 1);
    const float c = ctab[s * 32 + pair];
    const float sn = stab[s * 32 + pair];
    const size_t base = (size_t)t * D3_ + h * HD_ + pair * 2;
    float x0 = qkv[base], x1 = qkv[base + 1];
    qkv[base]     = x0 * c - x1 * sn;
    qkv[base + 1] = x0 * sn + x1 * c;
    x0 = qkv[base + D_]; x1 = qkv[base + D_ + 1];
    qkv[base + D_]     = x0 * c - x1 * sn;
    qkv[base + D_ + 1] = x0 * sn + x1 * c;
}

// ---------------------------------------------------------------------------
// Flash-style causal attention, f32, precise expf
// ---------------------------------------------------------------------------
__global__ __launch_bounds__(256) void attn_kernel(
    const float* __restrict__ qkv, float* __restrict__ out)
{
    __shared__ float kbuf[64][65];
    __shared__ float vbuf[64][65];
    __shared__ float qs[32][64];
    __shared__ float ps[4][8][64];

    const int b = blockIdx.z, h = blockIdx.y, qt = blockIdx.x;
    const int tid = threadIdx.x, wave = tid >> 6, lane = tid & 63;
    const int q0 = qt * 32;

    for (int i = tid; i < 32 * 64; i += 256) {
        const int qi = i >> 6, d = i & 63;
        const int t = b * S_ + q0 + qi;
        qs[qi][d] = qkv[(size_t)t * D3_ + h * HD_ + d];
    }

    float m[8], l[8], O[8];
#pragma unroll
    for (int qi = 0; qi < 8; qi++) { m[qi] = -INFINITY; l[qi] = 0.f; O[qi] = 0.f; }

    const int maxS = q0 + 31;
    for (int c0 = 0; c0 <= maxS; c0 += 64) {
        __syncthreads();
        for (int i = tid; i < 64 * 16; i += 256) {
            const int key = i >> 4, d4 = (i & 15) * 4;
            const int t = b * S_ + c0 + key;
            const float4 kv = *(const float4*)(qkv + (size_t)t * D3_ + D_ + h * HD_ + d4);
            const float4 vv = *(const float4*)(qkv + (size_t)t * D3_ + 2 * D_ + h * HD_ + d4);
            kbuf[key][d4 + 0] = kv.x; kbuf[key][d4 + 1] = kv.y;
            kbuf[key][d4 + 2] = kv.z; kbuf[key][d4 + 3] = kv.w;
            vbuf[key][d4 + 0] = vv.x; vbuf[key][d4 + 1] = vv.y;
            vbuf[key][d4 + 2] = vv.z; vbuf[key][d4 + 3] = vv.w;
        }
        __syncthreads();

        const int kglob = c0 + lane;
        float sc[8];
#pragma unroll
        for (int qi = 0; qi < 8; qi++) sc[qi] = 0.f;
#pragma unroll 8
        for (int d = 0; d < 64; d++) {
            const float kv = kbuf[lane][d];
#pragma unroll
            for (int qi = 0; qi < 8; qi++)
                sc[qi] = fmaf(qs[wave * 8 + qi][d], kv, sc[qi]);
        }
#pragma unroll
        for (int qi = 0; qi < 8; qi++) {
            const int s = q0 + wave * 8 + qi;
            float v = (kglob <= s) ? sc[qi] * 0.125f : -INFINITY;
            float cmax = v;
#pragma unroll
            for (int off = 32; off; off >>= 1) cmax = fmaxf(cmax, __shfl_xor(cmax, off));
            const float mnew = fmaxf(m[qi], cmax);
            const float alpha = expf(m[qi] - mnew);
            const float p = (v == -INFINITY) ? 0.f : expf(v - mnew);
            float psum = p;
#pragma unroll
            for (int off = 32; off; off >>= 1) psum += __shfl_xor(psum, off);
            l[qi] = l[qi] * alpha + psum;
            m[qi] = mnew;
            ps[wave][qi][lane] = p;
            sc[qi] = alpha;
        }
#pragma unroll
        for (int qi = 0; qi < 8; qi++) O[qi] *= sc[qi];
#pragma unroll 8
        for (int j = 0; j < 64; j++) {
            const float vv = vbuf[j][lane];
#pragma unroll
            for (int qi = 0; qi < 8; qi++)
                O[qi] = fmaf(ps[wave][qi][j], vv, O[qi]);
        }
    }

#pragma unroll
    for (int qi = 0; qi < 8; qi++) {
        const int t = b * S_ + q0 + wave * 8 + qi;
        out[(size_t)t * D_ + h * HD_ + lane] = O[qi] / l[qi];
    }
}

// ---------------------------------------------------------------------------
// Copy f32 (float4 granular)
// ---------------------------------------------------------------------------
__global__ __launch_bounds__(256) void copy_f32_kernel(
    const float* __restrict__ in, float* __restrict__ out, int n4)
{
    const int i = blockIdx.x * 256 + threadIdx.x;
    if (i < n4) ((float4*)out)[i] = ((const float4*)in)[i];
}

// ---------------------------------------------------------------------------
// Gating. bf16-rounded logits (XLA bf16@bf16->bf16), top-2 lowest-index
// tie-break, softmax weights -> cw; full softmax probs -> probs buffer.
// ---------------------------------------------------------------------------
__global__ __launch_bounds__(64) void gate_kernel(
    const ushort_t* __restrict__ xn2, const float* __restrict__ gate_w,
    float* __restrict__ cw, float* __restrict__ probs)
{
    const int t = blockIdx.x;
    const int lane = threadIdx.x;
    float acc[8] = {0, 0, 0, 0, 0, 0, 0, 0};
    for (int d = lane; d < D_; d += 64) {
        const float xv = bf2f(xn2[(size_t)t * D_ + d]);
        const float4 g0 = ((const float4*)(gate_w + d * 8))[0];
        const float4 g1 = ((const float4*)(gate_w + d * 8))[1];
        acc[0] = fmaf(xv, bf2f(f2bf(g0.x)), acc[0]);
        acc[1] = fmaf(xv, bf2f(f2bf(g0.y)), acc[1]);
        acc[2] = fmaf(xv, bf2f(f2bf(g0.z)), acc[2]);
        acc[3] = fmaf(xv, bf2f(f2bf(g0.w)), acc[3]);
        acc[4] = fmaf(xv, bf2f(f2bf(g1.x)), acc[4]);
        acc[5] = fmaf(xv, bf2f(f2bf(g1.y)), acc[5]);
        acc[6] = fmaf(xv, bf2f(f2bf(g1.z)), acc[6]);
        acc[7] = fmaf(xv, bf2f(f2bf(g1.w)), acc[7]);
    }
#pragma unroll
    for (int e = 0; e < 8; e++) {
#pragma unroll
        for (int off = 32; off; off >>= 1) acc[e] += __shfl_xor(acc[e], off);
        acc[e] = bf2f(f2bf(acc[e]));   // bf16 result of the bf16 matmul
    }

    if (lane == 0) {
        int i1 = 0;
        for (int e = 1; e < 8; e++) if (acc[e] > acc[i1]) i1 = e;
        int i2 = (i1 == 0) ? 1 : 0;
        for (int e = 0; e < 8; e++) if (e != i1 && acc[e] > acc[i2]) i2 = e;
        const float e2 = expf(acc[i2] - acc[i1]);
        const float w1 = 1.f / (1.f + e2);
        const float w2 = e2 * w1;
        for (int e = 0; e < 8; e++)
            cw[t * 8 + e] = (e == i1) ? w1 : ((e == i2) ? w2 : 0.f);
        const float mx = acc[i1];
        float se = 0.f, pe[8];
        for (int e = 0; e < 8; e++) { pe[e] = expf(acc[e] - mx); se += pe[e]; }
        const float inv = 1.f / se;
        for (int e = 0; e < 8; e++) probs[t * 8 + e] = pe[e] * inv;
    }
}

// ---------------------------------------------------------------------------
// dist = probs.mean(0); lb = E * sum(dist^2); writes out tail.
// ---------------------------------------------------------------------------
__global__ __launch_bounds__(256) void reduce_dist_kernel(
    const float* __restrict__ probs, float* __restrict__ out)
{
    __shared__ float part[256];
    __shared__ float dist8[8];
    const int tid = threadIdx.x;
    const int e = tid & 7, chunk = tid >> 3;   // 32 chunks
    float s = 0.f;
    for (int t = chunk; t < T_; t += 32) s += probs[t * 8 + e];
    part[tid] = s;
    __syncthreads();
    if (tid < 8) {
        float tot = 0.f;
        for (int c = 0; c < 32; c++) tot += part[c * 8 + tid];
        const float dv = tot * (1.0f / T_);
        dist8[tid] = dv;
        out[(size_t)T_ * D_ + 1 + tid] = dv;
    }
    __syncthreads();
    if (tid == 0) {
        float s2 = 0.f;
        for (int k = 0; k < 8; k++) s2 += dist8[k] * dist8[k];
        out[(size_t)T_ * D_] = (float)E_ * s2;
    }
}

// ---------------------------------------------------------------------------
// Launch
// ---------------------------------------------------------------------------
extern "C" void kernel_launch(void* const* d_in, const int* in_sizes, int n_in,
                              void* d_out, int out_size, void* d_ws, size_t ws_size,
                              hipStream_t stream)
{
    const float* x      = (const float*)d_in[0];
    const float* ln1_g  = (const float*)d_in[1];
    const float* ln1_b  = (const float*)d_in[2];
    const float* ln2_g  = (const float*)d_in[3];
    const float* ln2_b  = (const float*)d_in[4];
    const float* w_qkv  = (const float*)d_in[5];
    const float* w_o    = (const float*)d_in[6];
    const float* gate_w = (const float*)d_in[7];
    const float* w_gate = (const float*)d_in[8];
    const float* w_up   = (const float*)d_in[9];
    const float* w_down = (const float*)d_in[10];
    float* out = (float*)d_out;

    char* ws = (char*)d_ws;
    size_t off = 0;
    auto alloc = [&](size_t bytes) { size_t o = off; off += (bytes + 255) & ~(size_t)255; return o; };
    // persistent-through-MoE region
    ushort_t* wguT  = (ushort_t*)(ws + alloc((size_t)E_ * GU_ * D_ * 2));   // 58.7 MB
    ushort_t* wdT   = (ushort_t*)(ws + alloc((size_t)E_ * D_ * HID_ * 2));  // 29.4 MB
    float*    xn    = (float*)   (ws + alloc((size_t)T_ * D_ * 4));
    ushort_t* xn2   = (ushort_t*)(ws + alloc((size_t)T_ * D_ * 2));
    float*    cw    = (float*)   (ws + alloc((size_t)T_ * E_ * 4));
    float*    probs = (float*)   (ws + alloc((size_t)T_ * E_ * 4));
    float*    ctab  = (float*)   (ws + alloc((size_t)S_ * 32 * 4));
    float*    stab  = (float*)   (ws + alloc((size_t)S_ * 32 * 4));
    // scratch region: qkv/attnO/x1 are dead before MoE; hbufAll aliases them
    const size_t scratch0 = off;
    float*    qkv   = (float*)   (ws + alloc((size_t)T_ * D3_ * 4));
    float*    attnO = (float*)   (ws + alloc((size_t)T_ * D_ * 4));
    float*    x1    = (float*)   (ws + alloc((size_t)T_ * D_ * 4));
    ushort_t* hbufA = (ushort_t*)(ws + scratch0);   // E*T*HID bf16 = 58.7 MB
    (void)ws_size; (void)in_sizes; (void)n_in; (void)out_size;

    // weight transposes -> bf16 (N x K); gate/up interleaved into wguT
    hipLaunchKernelGGL(transpose_bf16_kernel, dim3(HID_ / 32, D_ / 32, E_), dim3(256), 0, stream,
                       w_gate, wguT, D_, HID_, 2, 0, (long)GU_ * D_);
    hipLaunchKernelGGL(transpose_bf16_kernel, dim3(HID_ / 32, D_ / 32, E_), dim3(256), 0, stream,
                       w_up, wguT, D_, HID_, 2, 1, (long)GU_ * D_);
    hipLaunchKernelGGL(transpose_bf16_kernel, dim3(D_ / 32, HID_ / 32, E_), dim3(256), 0, stream,
                       w_down, wdT, HID_, D_, 1, 0, (long)D_ * HID_);

    // RoPE tables
    hipLaunchKernelGGL(rope_table_kernel, dim3((S_ * 32 + 255) / 256), dim3(256), 0, stream,
                       ctab, stab);

    // LN1 (f32)
    hipLaunchKernelGGL(ln_kernel, dim3(T_), dim3(256), 0, stream,
                       x, ln1_g, ln1_b, xn, (ushort_t*)nullptr);

    // QKV f32 SGEMM
    hipLaunchKernelGGL(sgemm_kernel, dim3(D3_ / 128, T_ / 128), dim3(256), 0, stream,
                       xn, w_qkv, (const float*)nullptr, qkv, T_, D3_, D_);

    // RoPE
    hipLaunchKernelGGL(rope_kernel, dim3(T_ * H_ * 32 / 256), dim3(256), 0, stream,
                       qkv, ctab, stab);

    // attention
    hipLaunchKernelGGL(attn_kernel, dim3(S_ / 32, H_, B_), dim3(256), 0, stream, qkv, attnO);

    // W_O SGEMM + residual -> x1
    hipLaunchKernelGGL(sgemm_kernel, dim3(D_ / 128, T_ / 128), dim3(256), 0, stream,
                       attnO, w_o, x, x1, T_, D_, D_);

    // out x-region = x1 (down_kernel accumulates on top)
    hipLaunchKernelGGL(copy_f32_kernel, dim3(T_ * D_ / 4 / 256), dim3(256), 0, stream,
                       x1, out, T_ * D_ / 4);

    // LN2 (bf16)
    hipLaunchKernelGGL(ln_kernel, dim3(T_), dim3(256), 0, stream,
                       x1, ln2_g, ln2_b, (float*)nullptr, xn2);

    // gating + aux outputs
    hipLaunchKernelGGL(gate_kernel, dim3(T_), dim3(64), 0, stream, xn2, gate_w, cw, probs);
    hipLaunchKernelGGL(reduce_dist_kernel, dim3(1), dim3(256), 0, stream, probs, out);

    // MoE: fused gate+up (+silu) then weighted down accumulation, all experts
    hipLaunchKernelGGL(gateup_kernel, dim3(GU_ / 128, T_ / 128, E_), dim3(256), 0, stream,
                       xn2, wguT, hbufA);
    hipLaunchKernelGGL(down_kernel, dim3(D_ / 128, T_ / 128, E_), dim3(256), 0, stream,
                       hbufA, wdT, cw, out);
}

// Round 4
// 838.504 us; speedup vs baseline: 1.9561x; 1.2239x over previous
//
#include <hip/hip_runtime.h>
#include <hip/hip_bf16.h>
#include <math.h>

// ---------------------------------------------------------------------------
// Shapes (fixed by the problem)
// ---------------------------------------------------------------------------
#define B_    4
#define S_    512
#define D_    1024
#define T_    2048          // B*S tokens
#define H_    16
#define HD_   64
#define E_    8
#define HID_  1792
#define D3_   3072
#define GU_   (2 * HID_)    // 3584 interleaved gate/up columns

typedef unsigned short ushort_t;
typedef __bf16 bf16x8 __attribute__((ext_vector_type(8)));
typedef float  floatx4 __attribute__((ext_vector_type(4)));

__device__ inline float bf2f(ushort_t u) {
    return __uint_as_float(((unsigned)u) << 16);
}
__device__ inline ushort_t f2bf(float f) {
    __hip_bfloat16 h = __float2bfloat16(f);
    return __builtin_bit_cast(ushort_t, h);
}

// async 16B/lane global->LDS; lds dest wave-uniform base (+lane*16 by HW)
__device__ __forceinline__ void gl2lds16(const ushort_t* g, ushort_t* l) {
    __builtin_amdgcn_global_load_lds(
        (const __attribute__((address_space(1))) void*)g,
        (__attribute__((address_space(3))) void*)l, 16, 0, 0);
}

// ---------------------------------------------------------------------------
// Transpose + fp32->bf16: in (z,R,C) f32 -> out[z*outEstride + (c*mul+add)*R + r]
// ---------------------------------------------------------------------------
__global__ __launch_bounds__(256) void transpose_bf16_kernel(
    const float* __restrict__ in, ushort_t* __restrict__ out,
    int R, int C, int mul, int add, long outEstride)
{
    __shared__ float tile[32][33];
    const int bx = blockIdx.x * 32;           // c
    const int by = blockIdx.y * 32;           // r
    const size_t iofs = (size_t)blockIdx.z * R * C;
    const size_t oofs = (size_t)blockIdx.z * outEstride;
    const int tx = threadIdx.x & 31;
    const int ty = threadIdx.x >> 5;          // 0..7
#pragma unroll
    for (int i = 0; i < 4; i++) {
        int r = by + ty + i * 8;
        tile[ty + i * 8][tx] = in[iofs + (size_t)r * C + bx + tx];
    }
    __syncthreads();
#pragma unroll
    for (int i = 0; i < 4; i++) {
        int c = bx + ty + i * 8;
        out[oofs + (size_t)(c * mul + add) * R + by + tx] = f2bf(tile[tx][ty + i * 8]);
    }
}

// ---------------------------------------------------------------------------
// LayerNorm: x (rows x 1024) f32 -> f32 out and/or bf16 out
// ---------------------------------------------------------------------------
__global__ __launch_bounds__(256) void ln_kernel(
    const float* __restrict__ x, const float* __restrict__ g,
    const float* __restrict__ b, float* __restrict__ outf,
    ushort_t* __restrict__ outb)
{
    const int t = blockIdx.x;
    const int tid = threadIdx.x;
    const int wave = tid >> 6, lane = tid & 63;
    const float4 v = ((const float4*)(x + (size_t)t * D_))[tid];

    float s = v.x + v.y + v.z + v.w;
#pragma unroll
    for (int off = 32; off; off >>= 1) s += __shfl_xor(s, off);
    __shared__ float red1[4];
    __shared__ float red2[4];
    if (lane == 0) red1[wave] = s;
    __syncthreads();
    const float mu = (red1[0] + red1[1] + red1[2] + red1[3]) * (1.0f / D_);

    const float dx = v.x - mu, dy = v.y - mu, dz = v.z - mu, dw = v.w - mu;
    float vs = dx * dx + dy * dy + dz * dz + dw * dw;
#pragma unroll
    for (int off = 32; off; off >>= 1) vs += __shfl_xor(vs, off);
    if (lane == 0) red2[wave] = vs;
    __syncthreads();
    const float var = (red2[0] + red2[1] + red2[2] + red2[3]) * (1.0f / D_);
    const float rs = 1.0f / sqrtf(var + 1e-5f);

    const float4 gg = ((const float4*)g)[tid];
    const float4 bb = ((const float4*)b)[tid];
    float4 o;
    o.x = dx * rs * gg.x + bb.x;
    o.y = dy * rs * gg.y + bb.y;
    o.z = dz * rs * gg.z + bb.z;
    o.w = dw * rs * gg.w + bb.w;
    if (outf) ((float4*)(outf + (size_t)t * D_))[tid] = o;
    if (outb) {
        ushort4 ob;
        ob.x = f2bf(o.x); ob.y = f2bf(o.y); ob.z = f2bf(o.z); ob.w = f2bf(o.w);
        ((ushort4*)(outb + (size_t)t * D_))[tid] = ob;
    }
}

// ---------------------------------------------------------------------------
// f32 SGEMM: C(MxTN*?) tiles TM x 64, BK=16, 256 thr, (TM/16)x4 per thread.
// k-major LDS: As[k][m] (A-reads broadcast, free), Bs[k][n] (16 distinct
// float4 @16B stride = all 32 banks, conflict-free).
// ---------------------------------------------------------------------------
template<int TM>
__global__ __launch_bounds__(256) void sgemm_kernel(
    const float* __restrict__ A, const float* __restrict__ B,
    const float* __restrict__ res, float* __restrict__ C,
    int M, int N, int K)
{
    constexpr int RM  = TM / 16;      // rows per thread (8 or 4)
    constexpr int TPR = 256 / TM;     // threads per A row (2 or 4)
    constexpr int KF  = 16 / TPR;     // k-floats staged per thread (8 or 4)
    __shared__ float As[16][TM + 4];
    __shared__ float Bs[16][68];
    const int tid = threadIdx.x;
    const int m0 = blockIdx.y * TM, n0 = blockIdx.x * 64;
    const int tx = tid & 15, ty = tid >> 4;

    float acc[RM][4] = {};

    const int arow = tid / TPR;            // 0..TM-1
    const int akk  = (tid % TPR) * KF;     // 0..15 step KF
    const int bk = tid >> 4;               // 0..15
    const int bc = (tid & 15) * 4;         // 0..60

    const float* Ap = A + (size_t)(m0 + arow) * K + akk;
    const float* Bp = B + (size_t)bk * N + n0 + bc;

    for (int k0 = 0; k0 < K; k0 += 16) {
        float av[KF];
#pragma unroll
        for (int f = 0; f < KF / 4; f++) {
            const float4 t = *(const float4*)(Ap + k0 + f * 4);
            av[f * 4 + 0] = t.x; av[f * 4 + 1] = t.y;
            av[f * 4 + 2] = t.z; av[f * 4 + 3] = t.w;
        }
        const float4 bv = *(const float4*)(Bp + (size_t)k0 * N);
        __syncthreads();
#pragma unroll
        for (int i = 0; i < KF; i++) As[akk + i][arow] = av[i];
        *(float4*)&Bs[bk][bc] = bv;
        __syncthreads();
#pragma unroll
        for (int k = 0; k < 16; k++) {
            float a[RM];
#pragma unroll
            for (int f = 0; f < RM / 4; f++) {
                const float4 t = *(const float4*)&As[k][ty * RM + f * 4];
                a[f * 4 + 0] = t.x; a[f * 4 + 1] = t.y;
                a[f * 4 + 2] = t.z; a[f * 4 + 3] = t.w;
            }
            const float4 bb = *(const float4*)&Bs[k][tx * 4];
            const float bj[4] = {bb.x, bb.y, bb.z, bb.w};
#pragma unroll
            for (int i = 0; i < RM; i++)
#pragma unroll
                for (int j = 0; j < 4; j++)
                    acc[i][j] = fmaf(a[i], bj[j], acc[i][j]);
        }
    }

#pragma unroll
    for (int i = 0; i < RM; i++) {
        const int row = m0 + ty * RM + i;
        const size_t base = (size_t)row * N + n0 + tx * 4;
        float4 o;
        o.x = acc[i][0]; o.y = acc[i][1]; o.z = acc[i][2]; o.w = acc[i][3];
        if (res) {
            const float4 r0 = *(const float4*)(res + base);
            o.x += r0.x; o.y += r0.y; o.z += r0.z; o.w += r0.w;
        }
        *(float4*)(C + base) = o;
    }
}

// ---------------------------------------------------------------------------
// Routed fused gate+up MoE GEMM: rows gathered from per-expert token lists.
// Bgu: per-expert 3584 x 1024 bf16, g/u columns interleaved.
// Hc[e*T + listRow][HID]: silu(g)*u. grid (28, 16, E); blocks past count exit.
// ---------------------------------------------------------------------------
__global__ __launch_bounds__(256) void gateup_idx_kernel(
    const ushort_t* __restrict__ A, const ushort_t* __restrict__ Bgu,
    const int* __restrict__ cnt, const int* __restrict__ tok,
    ushort_t* __restrict__ Hc)
{
    const int e = blockIdx.z;
    const int cntE = cnt[e];
    const int row0 = blockIdx.y * 128;
    if (row0 >= cntE) return;
    const int col0 = blockIdx.x * 128;
    const ushort_t* Bt = Bgu + (size_t)e * GU_ * D_;
    ushort_t* Hp = Hc + (size_t)e * T_ * HID_;

    __shared__ __align__(16) ushort_t As[128 * 32];
    __shared__ __align__(16) ushort_t Bs[128 * 32];
    const int tid = threadIdx.x, w = tid >> 6, lane = tid & 63;
    const int lr = lane >> 2, lc = (lane & 3) * 8;
    const int wm = (w >> 1) * 64, wn = (w & 1) * 64;
    const int lm = lane & 15, lq = lane >> 4;

    floatx4 acc[4][4] = {};

    int r0c = row0 + w * 16 + lr;  if (r0c > cntE - 1) r0c = cntE - 1;
    int r1c = row0 + 64 + w * 16 + lr; if (r1c > cntE - 1) r1c = cntE - 1;
    const ushort_t* Ap0 = A + (size_t)tok[e * T_ + r0c] * D_ + lc;
    const ushort_t* Ap1 = A + (size_t)tok[e * T_ + r1c] * D_ + lc;
    const ushort_t* Bp = Bt + (size_t)(col0 + w * 16 + lr) * D_ + lc;
    ushort_t* lA = As + w * 512;
    ushort_t* lB = Bs + w * 512;

    for (int k0 = 0; k0 < D_; k0 += 32) {
        __syncthreads();
        gl2lds16(Ap0 + k0, lA);
        gl2lds16(Ap1 + k0, lA + 2048);
        gl2lds16(Bp + k0, lB);
        gl2lds16(Bp + k0 + (size_t)64 * D_, lB + 2048);
        __syncthreads();
        bf16x8 a[4], b[4];
#pragma unroll
        for (int i = 0; i < 4; i++)
            a[i] = *(const bf16x8*)(As + (wm + i * 16 + lm) * 32 + lq * 8);
#pragma unroll
        for (int j = 0; j < 4; j++)
            b[j] = *(const bf16x8*)(Bs + (wn + j * 16 + lm) * 32 + lq * 8);
#pragma unroll
        for (int i = 0; i < 4; i++)
#pragma unroll
            for (int j = 0; j < 4; j++)
                acc[i][j] = __builtin_amdgcn_mfma_f32_16x16x32_bf16(a[i], b[j], acc[i][j], 0, 0, 0);
    }

    // epilogue: adjacent lanes hold (gate, up) for the same hidden unit
#pragma unroll
    for (int i = 0; i < 4; i++)
#pragma unroll
        for (int j = 0; j < 4; j++)
#pragma unroll
            for (int r = 0; r < 4; r++) {
                const float v = acc[i][j][r];
                const float vp = __shfl_xor(v, 1);
                const float g = (lm & 1) ? vp : v;
                const float u = (lm & 1) ? v : vp;
                const float h = g / (1.f + __expf(-g)) * u;
                if (!(lm & 1)) {
                    const int row = row0 + wm + i * 16 + lq * 4 + r;
                    const int col = col0 + wn + j * 16 + lm;    // even
                    Hp[(size_t)row * HID_ + (col >> 1)] = f2bf(h);
                }
            }
}

// ---------------------------------------------------------------------------
// Routed MoE down GEMM: out[tok[r]] += wt[r] * (Hc[e] @ wd[e]^T). grid (8,16,E)
// ---------------------------------------------------------------------------
__global__ __launch_bounds__(256) void down_idx_kernel(
    const ushort_t* __restrict__ Hc, const ushort_t* __restrict__ Wd,
    const int* __restrict__ cnt, const int* __restrict__ tok,
    const float* __restrict__ wt, float* __restrict__ out)
{
    const int e = blockIdx.z;
    const int cntE = cnt[e];
    const int row0 = blockIdx.y * 128;
    if (row0 >= cntE) return;
    const int col0 = blockIdx.x * 128;
    const ushort_t* A = Hc + (size_t)e * T_ * HID_;
    const ushort_t* Bt = Wd + (size_t)e * D_ * HID_;

    __shared__ __align__(16) ushort_t As[128 * 32];
    __shared__ __align__(16) ushort_t Bs[128 * 32];
    const int tid = threadIdx.x, w = tid >> 6, lane = tid & 63;
    const int lr = lane >> 2, lc = (lane & 3) * 8;
    const int wm = (w >> 1) * 64, wn = (w & 1) * 64;
    const int lm = lane & 15, lq = lane >> 4;

    floatx4 acc[4][4] = {};

    const ushort_t* Ap = A + (size_t)(row0 + w * 16 + lr) * HID_ + lc;
    const ushort_t* Bp = Bt + (size_t)(col0 + w * 16 + lr) * HID_ + lc;
    ushort_t* lA = As + w * 512;
    ushort_t* lB = Bs + w * 512;

    for (int k0 = 0; k0 < HID_; k0 += 32) {
        __syncthreads();
        gl2lds16(Ap + k0, lA);
        gl2lds16(Ap + k0 + (size_t)64 * HID_, lA + 2048);
        gl2lds16(Bp + k0, lB);
        gl2lds16(Bp + k0 + (size_t)64 * HID_, lB + 2048);
        __syncthreads();
        bf16x8 a[4], b[4];
#pragma unroll
        for (int i = 0; i < 4; i++)
            a[i] = *(const bf16x8*)(As + (wm + i * 16 + lm) * 32 + lq * 8);
#pragma unroll
        for (int j = 0; j < 4; j++)
            b[j] = *(const bf16x8*)(Bs + (wn + j * 16 + lm) * 32 + lq * 8);
#pragma unroll
        for (int i = 0; i < 4; i++)
#pragma unroll
            for (int j = 0; j < 4; j++)
                acc[i][j] = __builtin_amdgcn_mfma_f32_16x16x32_bf16(a[i], b[j], acc[i][j], 0, 0, 0);
    }

#pragma unroll
    for (int i = 0; i < 4; i++)
#pragma unroll
        for (int r = 0; r < 4; r++) {
            const int row = row0 + wm + i * 16 + lq * 4 + r;
            if (row < cntE) {
                const int t = tok[e * T_ + row];
                const float scale = wt[e * T_ + row];
#pragma unroll
                for (int j = 0; j < 4; j++) {
                    const int col = col0 + wn + j * 16 + lm;
                    atomicAdd(&out[(size_t)t * D_ + col], scale * acc[i][j][r]);
                }
            }
        }
}

// ---------------------------------------------------------------------------
// RoPE cos/sin tables (np f32 semantics via f64 pow/cos/sin)
// ---------------------------------------------------------------------------
__global__ __launch_bounds__(256) void rope_table_kernel(
    float* __restrict__ ctab, float* __restrict__ stab)
{
    const int i = blockIdx.x * 256 + threadIdx.x;   // S_*32
    if (i >= S_ * 32) return;
    const int s = i >> 5, p = i & 31;
    const double e = (double)(2 * p) / 64.0;
    const float pf = (float)pow(10000.0, e);
    const float invf = 1.0f / pf;
    const float fr = (float)s * invf;
    ctab[i] = (float)cos((double)fr);
    stab[i] = (float)sin((double)fr);
}

// ---------------------------------------------------------------------------
// RoPE in-place on qkv f32 (T x 3072): rotate q and k
// ---------------------------------------------------------------------------
__global__ __launch_bounds__(256) void rope_kernel(
    float* __restrict__ qkv, const float* __restrict__ ctab,
    const float* __restrict__ stab)
{
    const int n = blockIdx.x * 256 + threadIdx.x;     // T*H*32
    const int pair = n & 31;
    const int h = (n >> 5) & 15;
    const int t = n >> 9;
    const int s = t & (S_ - 1);
    const float c = ctab[s * 32 + pair];
    const float sn = stab[s * 32 + pair];
    const size_t base = (size_t)t * D3_ + h * HD_ + pair * 2;
    float x0 = qkv[base], x1 = qkv[base + 1];
    qkv[base]     = x0 * c - x1 * sn;
    qkv[base + 1] = x0 * sn + x1 * c;
    x0 = qkv[base + D_]; x1 = qkv[base + D_ + 1];
    qkv[base + D_]     = x0 * c - x1 * sn;
    qkv[base + D_ + 1] = x0 * sn + x1 * c;
}

// ---------------------------------------------------------------------------
// Flash-style causal attention, f32, precise expf
// ---------------------------------------------------------------------------
__global__ __launch_bounds__(256) void attn_kernel(
    const float* __restrict__ qkv, float* __restrict__ out)
{
    __shared__ float kbuf[64][65];
    __shared__ float vbuf[64][65];
    __shared__ float qs[32][64];
    __shared__ float ps[4][8][64];

    const int b = blockIdx.z, h = blockIdx.y, qt = blockIdx.x;
    const int tid = threadIdx.x, wave = tid >> 6, lane = tid & 63;
    const int q0 = qt * 32;

    for (int i = tid; i < 32 * 64; i += 256) {
        const int qi = i >> 6, d = i & 63;
        const int t = b * S_ + q0 + qi;
        qs[qi][d] = qkv[(size_t)t * D3_ + h * HD_ + d];
    }

    float m[8], l[8], O[8];
#pragma unroll
    for (int qi = 0; qi < 8; qi++) { m[qi] = -INFINITY; l[qi] = 0.f; O[qi] = 0.f; }

    const int maxS = q0 + 31;
    for (int c0 = 0; c0 <= maxS; c0 += 64) {
        __syncthreads();
        for (int i = tid; i < 64 * 16; i += 256) {
            const int key = i >> 4, d4 = (i & 15) * 4;
            const int t = b * S_ + c0 + key;
            const float4 kv = *(const float4*)(qkv + (size_t)t * D3_ + D_ + h * HD_ + d4);
            const float4 vv = *(const float4*)(qkv + (size_t)t * D3_ + 2 * D_ + h * HD_ + d4);
            kbuf[key][d4 + 0] = kv.x; kbuf[key][d4 + 1] = kv.y;
            kbuf[key][d4 + 2] = kv.z; kbuf[key][d4 + 3] = kv.w;
            vbuf[key][d4 + 0] = vv.x; vbuf[key][d4 + 1] = vv.y;
            vbuf[key][d4 + 2] = vv.z; vbuf[key][d4 + 3] = vv.w;
        }
        __syncthreads();

        const int kglob = c0 + lane;
        float sc[8];
#pragma unroll
        for (int qi = 0; qi < 8; qi++) sc[qi] = 0.f;
#pragma unroll 8
        for (int d = 0; d < 64; d++) {
            const float kv = kbuf[lane][d];
#pragma unroll
            for (int qi = 0; qi < 8; qi++)
                sc[qi] = fmaf(qs[wave * 8 + qi][d], kv, sc[qi]);
        }
#pragma unroll
        for (int qi = 0; qi < 8; qi++) {
            const int s = q0 + wave * 8 + qi;
            float v = (kglob <= s) ? sc[qi] * 0.125f : -INFINITY;
            float cmax = v;
#pragma unroll
            for (int off = 32; off; off >>= 1) cmax = fmaxf(cmax, __shfl_xor(cmax, off));
            const float mnew = fmaxf(m[qi], cmax);
            const float alpha = expf(m[qi] - mnew);
            const float p = (v == -INFINITY) ? 0.f : expf(v - mnew);
            float psum = p;
#pragma unroll
            for (int off = 32; off; off >>= 1) psum += __shfl_xor(psum, off);
            l[qi] = l[qi] * alpha + psum;
            m[qi] = mnew;
            ps[wave][qi][lane] = p;
            sc[qi] = alpha;
        }
#pragma unroll
        for (int qi = 0; qi < 8; qi++) O[qi] *= sc[qi];
#pragma unroll 8
        for (int j = 0; j < 64; j++) {
            const float vv = vbuf[j][lane];
#pragma unroll
            for (int qi = 0; qi < 8; qi++)
                O[qi] = fmaf(ps[wave][qi][j], vv, O[qi]);
        }
    }

#pragma unroll
    for (int qi = 0; qi < 8; qi++) {
        const int t = b * S_ + q0 + wave * 8 + qi;
        out[(size_t)t * D_ + h * HD_ + lane] = O[qi] / l[qi];
    }
}

// ---------------------------------------------------------------------------
// Copy f32 (float4 granular)
// ---------------------------------------------------------------------------
__global__ __launch_bounds__(256) void copy_f32_kernel(
    const float* __restrict__ in, float* __restrict__ out, int n4)
{
    const int i = blockIdx.x * 256 + threadIdx.x;
    if (i < n4) ((float4*)out)[i] = ((const float4*)in)[i];
}

// ---------------------------------------------------------------------------
// Gating + routing. bf16-rounded logits, top-2 lowest-index tie-break;
// scatters (token, weight) into per-expert lists; probs -> buffer.
// ---------------------------------------------------------------------------
__global__ __launch_bounds__(64) void gate_kernel(
    const ushort_t* __restrict__ xn2, const float* __restrict__ gate_w,
    int* __restrict__ cnt, int* __restrict__ tok, float* __restrict__ wt,
    float* __restrict__ probs)
{
    const int t = blockIdx.x;
    const int lane = threadIdx.x;
    float acc[8] = {0, 0, 0, 0, 0, 0, 0, 0};
    for (int d = lane; d < D_; d += 64) {
        const float xv = bf2f(xn2[(size_t)t * D_ + d]);
        const float4 g0 = ((const float4*)(gate_w + d * 8))[0];
        const float4 g1 = ((const float4*)(gate_w + d * 8))[1];
        acc[0] = fmaf(xv, bf2f(f2bf(g0.x)), acc[0]);
        acc[1] = fmaf(xv, bf2f(f2bf(g0.y)), acc[1]);
        acc[2] = fmaf(xv, bf2f(f2bf(g0.z)), acc[2]);
        acc[3] = fmaf(xv, bf2f(f2bf(g0.w)), acc[3]);
        acc[4] = fmaf(xv, bf2f(f2bf(g1.x)), acc[4]);
        acc[5] = fmaf(xv, bf2f(f2bf(g1.y)), acc[5]);
        acc[6] = fmaf(xv, bf2f(f2bf(g1.z)), acc[6]);
        acc[7] = fmaf(xv, bf2f(f2bf(g1.w)), acc[7]);
    }
#pragma unroll
    for (int e = 0; e < 8; e++) {
#pragma unroll
        for (int off = 32; off; off >>= 1) acc[e] += __shfl_xor(acc[e], off);
        acc[e] = bf2f(f2bf(acc[e]));   // bf16 result of the bf16 matmul
    }

    if (lane == 0) {
        int i1 = 0;
        for (int e = 1; e < 8; e++) if (acc[e] > acc[i1]) i1 = e;
        int i2 = (i1 == 0) ? 1 : 0;
        for (int e = 0; e < 8; e++) if (e != i1 && acc[e] > acc[i2]) i2 = e;
        const float e2 = expf(acc[i2] - acc[i1]);
        const float w1 = 1.f / (1.f + e2);
        const float w2 = e2 * w1;
        const int p1 = atomicAdd(&cnt[i1], 1);
        tok[i1 * T_ + p1] = t; wt[i1 * T_ + p1] = w1;
        const int p2 = atomicAdd(&cnt[i2], 1);
        tok[i2 * T_ + p2] = t; wt[i2 * T_ + p2] = w2;
        const float mx = acc[i1];
        float se = 0.f, pe[8];
        for (int e = 0; e < 8; e++) { pe[e] = expf(acc[e] - mx); se += pe[e]; }
        const float inv = 1.f / se;
        for (int e = 0; e < 8; e++) probs[t * 8 + e] = pe[e] * inv;
    }
}

__global__ void zero_route_kernel(int* __restrict__ cnt)
{
    if (threadIdx.x < 8) cnt[threadIdx.x] = 0;
}

// ---------------------------------------------------------------------------
// dist = probs.mean(0); lb = E * sum(dist^2); writes out tail.
// ---------------------------------------------------------------------------
__global__ __launch_bounds__(256) void reduce_dist_kernel(
    const float* __restrict__ probs, float* __restrict__ out)
{
    __shared__ float part[256];
    __shared__ float dist8[8];
    const int tid = threadIdx.x;
    const int e = tid & 7, chunk = tid >> 3;   // 32 chunks
    float s = 0.f;
    for (int t = chunk; t < T_; t += 32) s += probs[t * 8 + e];
    part[tid] = s;
    __syncthreads();
    if (tid < 8) {
        float tot = 0.f;
        for (int c = 0; c < 32; c++) tot += part[c * 8 + tid];
        const float dv = tot * (1.0f / T_);
        dist8[tid] = dv;
        out[(size_t)T_ * D_ + 1 + tid] = dv;
    }
    __syncthreads();
    if (tid == 0) {
        float s2 = 0.f;
        for (int k = 0; k < 8; k++) s2 += dist8[k] * dist8[k];
        out[(size_t)T_ * D_] = (float)E_ * s2;
    }
}

// ---------------------------------------------------------------------------
// Launch
// ---------------------------------------------------------------------------
extern "C" void kernel_launch(void* const* d_in, const int* in_sizes, int n_in,
                              void* d_out, int out_size, void* d_ws, size_t ws_size,
                              hipStream_t stream)
{
    const float* x      = (const float*)d_in[0];
    const float* ln1_g  = (const float*)d_in[1];
    const float* ln1_b  = (const float*)d_in[2];
    const float* ln2_g  = (const float*)d_in[3];
    const float* ln2_b  = (const float*)d_in[4];
    const float* w_qkv  = (const float*)d_in[5];
    const float* w_o    = (const float*)d_in[6];
    const float* gate_w = (const float*)d_in[7];
    const float* w_gate = (const float*)d_in[8];
    const float* w_up   = (const float*)d_in[9];
    const float* w_down = (const float*)d_in[10];
    float* out = (float*)d_out;

    char* ws = (char*)d_ws;
    size_t off = 0;
    auto alloc = [&](size_t bytes) { size_t o = off; off += (bytes + 255) & ~(size_t)255; return o; };
    // persistent-through-MoE region
    ushort_t* wguT  = (ushort_t*)(ws + alloc((size_t)E_ * GU_ * D_ * 2));   // 58.7 MB
    ushort_t* wdT   = (ushort_t*)(ws + alloc((size_t)E_ * D_ * HID_ * 2));  // 29.4 MB
    float*    xn    = (float*)   (ws + alloc((size_t)T_ * D_ * 4));
    ushort_t* xn2   = (ushort_t*)(ws + alloc((size_t)T_ * D_ * 2));
    int*      cnt   = (int*)     (ws + alloc(64));
    int*      tok   = (int*)     (ws + alloc((size_t)E_ * T_ * 4));
    float*    wt    = (float*)   (ws + alloc((size_t)E_ * T_ * 4));
    float*    probs = (float*)   (ws + alloc((size_t)T_ * E_ * 4));
    float*    ctab  = (float*)   (ws + alloc((size_t)S_ * 32 * 4));
    float*    stab  = (float*)   (ws + alloc((size_t)S_ * 32 * 4));
    // scratch region: qkv/attnO/x1 dead before MoE; Hc aliases (58.7 MB > 40 MB)
    const size_t scratch0 = alloc((size_t)E_ * T_ * HID_ * 2);
    float*    qkv   = (float*)   (ws + scratch0);
    float*    attnO = (float*)   (ws + scratch0 + (size_t)T_ * D3_ * 4);
    float*    x1    = (float*)   (ws + scratch0 + (size_t)T_ * D3_ * 4 + (size_t)T_ * D_ * 4);
    ushort_t* Hc    = (ushort_t*)(ws + scratch0);
    (void)ws_size; (void)in_sizes; (void)n_in; (void)out_size;

    // weight transposes -> bf16 (N x K); gate/up interleaved into wguT
    hipLaunchKernelGGL(transpose_bf16_kernel, dim3(HID_ / 32, D_ / 32, E_), dim3(256), 0, stream,
                       w_gate, wguT, D_, HID_, 2, 0, (long)GU_ * D_);
    hipLaunchKernelGGL(transpose_bf16_kernel, dim3(HID_ / 32, D_ / 32, E_), dim3(256), 0, stream,
                       w_up, wguT, D_, HID_, 2, 1, (long)GU_ * D_);
    hipLaunchKernelGGL(transpose_bf16_kernel, dim3(D_ / 32, HID_ / 32, E_), dim3(256), 0, stream,
                       w_down, wdT, HID_, D_, 1, 0, (long)D_ * HID_);

    // RoPE tables
    hipLaunchKernelGGL(rope_table_kernel, dim3((S_ * 32 + 255) / 256), dim3(256), 0, stream,
                       ctab, stab);

    // LN1 (f32)
    hipLaunchKernelGGL(ln_kernel, dim3(T_), dim3(256), 0, stream,
                       x, ln1_g, ln1_b, xn, (ushort_t*)nullptr);

    // QKV f32 SGEMM: 128x64 tiles -> 48x16 = 768 blocks
    hipLaunchKernelGGL((sgemm_kernel<128>), dim3(D3_ / 64, T_ / 128), dim3(256), 0, stream,
                       xn, w_qkv, (const float*)nullptr, qkv, T_, D3_, D_);

    // RoPE
    hipLaunchKernelGGL(rope_kernel, dim3(T_ * H_ * 32 / 256), dim3(256), 0, stream,
                       qkv, ctab, stab);

    // attention
    hipLaunchKernelGGL(attn_kernel, dim3(S_ / 32, H_, B_), dim3(256), 0, stream, qkv, attnO);

    // W_O SGEMM + residual -> x1: 64x64 tiles -> 16x32 = 512 blocks
    hipLaunchKernelGGL((sgemm_kernel<64>), dim3(D_ / 64, T_ / 64), dim3(256), 0, stream,
                       attnO, w_o, x, x1, T_, D_, D_);

    // out x-region = x1 (down_idx accumulates on top)
    hipLaunchKernelGGL(copy_f32_kernel, dim3(T_ * D_ / 4 / 256), dim3(256), 0, stream,
                       x1, out, T_ * D_ / 4);

    // LN2 (bf16)
    hipLaunchKernelGGL(ln_kernel, dim3(T_), dim3(256), 0, stream,
                       x1, ln2_g, ln2_b, (float*)nullptr, xn2);

    // gating + routing + aux outputs
    hipLaunchKernelGGL(zero_route_kernel, dim3(1), dim3(64), 0, stream, cnt);
    hipLaunchKernelGGL(gate_kernel, dim3(T_), dim3(64), 0, stream,
                       xn2, gate_w, cnt, tok, wt, probs);
    hipLaunchKernelGGL(reduce_dist_kernel, dim3(1), dim3(256), 0, stream, probs, out);

    // MoE routed: fused gate+up (+silu), then weighted down accumulation
    hipLaunchKernelGGL(gateup_idx_kernel, dim3(GU_ / 128, T_ / 128, E_), dim3(256), 0, stream,
                       xn2, wguT, cnt, tok, Hc);
    hipLaunchKernelGGL(down_idx_kernel, dim3(D_ / 128, T_ / 128, E_), dim3(256), 0, stream,
                       Hc, wdT, cnt, tok, wt, out);
}